// Round 1
// baseline (308.403 us; speedup 1.0000x reference)
//
#include <hip/hip_runtime.h>

// 19x19 box-sum, reflect pad 9, input (16,3,1024,1024) f32.
// V2: horizontal pass reads straight from global (float4 into registers,
// sliding sum in regs) -> only `mid` lives in LDS (21.3 KB -> 7 blocks/CU,
// was 48.6 KB -> 3 blocks/CU). Vertical pass unchanged (coalesced stores).

#define H   1024
#define W   1024
#define RAD 9
#define TS  64
#define IT  82          // mid rows: TS + 2*RAD
#define MSTR 65         // mid stride: bank=(r+c)%32 diagonal, 2-way max (free)

__global__ __launch_bounds__(256, 7)
void boxsum19_kernel(const float* __restrict__ in, float* __restrict__ out) {
    __shared__ float mid[IT * MSTR];   // 82 x 65 x 4B = 21,320 B

    const int bx = blockIdx.x, by = blockIdx.y;
    const int tx0 = bx * TS, ty0 = by * TS;
    const size_t img_off = (size_t)blockIdx.z * (size_t)(H * W);
    const float* __restrict__ inp  = in  + img_off;
    float* __restrict__       outp = out + img_off;
    const int tid = threadIdx.x;

    // ---- Stage A: horizontal 19-tap sliding sums, global -> regs -> mid ----
    // 328 tasks: (row r in [0,82)) x (segment s in [0,4)).
    // Task covers output cols [16s, 16s+16) of mid row r; needs global x in
    // [tx0+16s-9, tx0+16s+25). Load the 16B-aligned 40-float superset
    // [tx0+16s-12, tx0+16s+28) as 10 float4s.
    {
        const bool edge_x = (bx == 0) || (bx == (W / TS - 1));  // block-uniform
        for (int task = tid; task < IT * 4; task += 256) {
            const int r = task >> 2;
            const int s = task & 3;
            int gy = ty0 + r - RAD;
            gy = (gy < 0) ? -gy : ((gy > H - 1) ? (2 * (H - 1) - gy) : gy);
            const float* __restrict__ rowp = inp + (size_t)gy * W;
            const int xb = tx0 + 16 * s - 12;   // multiple of 4 floats -> 16B aligned

            float v[40];                         // fully static indexing -> VGPRs
            if (!edge_x) {
                #pragma unroll
                for (int q = 0; q < 10; ++q) {
                    const float4 f = *reinterpret_cast<const float4*>(rowp + xb + 4 * q);
                    v[4*q+0] = f.x; v[4*q+1] = f.y; v[4*q+2] = f.z; v[4*q+3] = f.w;
                }
            } else {
                #pragma unroll
                for (int q = 0; q < 40; ++q) {   // reflect-x scalar fallback
                    int gx = xb + q;
                    gx = (gx < 0) ? -gx : ((gx > W - 1) ? (2 * (W - 1) - gx) : gx);
                    v[q] = rowp[gx];
                }
            }
            // out(i) = sum v[i+3 .. i+21]
            float sum = 0.f;
            #pragma unroll
            for (int k = 0; k < 19; ++k) sum += v[3 + k];
            float* __restrict__ mrow = &mid[r * MSTR + 16 * s];
            mrow[0] = sum;
            #pragma unroll
            for (int i = 1; i < 16; ++i) {
                sum += v[21 + i] - v[2 + i];
                mrow[i] = sum;
            }
        }
    }
    __syncthreads();

    // ---- Stage B: vertical 19-tap sliding sums from mid, coalesced stores ----
    {
        const int c  = tid & 63;
        const int r0 = (tid >> 6) * 16;
        float s = 0.f;
        #pragma unroll
        for (int k = 0; k < 19; ++k) s += mid[(r0 + k) * MSTR + c];
        outp[(size_t)(ty0 + r0) * W + (tx0 + c)] = s;
        #pragma unroll
        for (int i = 1; i < 16; ++i) {
            s += mid[(r0 + 18 + i) * MSTR + c]
               - mid[(r0 + i - 1) * MSTR + c];
            outp[(size_t)(ty0 + r0 + i) * W + (tx0 + c)] = s;
        }
    }
}

extern "C" void kernel_launch(void* const* d_in, const int* in_sizes, int n_in,
                              void* d_out, int out_size, void* d_ws, size_t ws_size,
                              hipStream_t stream) {
    const float* in = (const float*)d_in[0];
    float* out = (float*)d_out;
    dim3 grid(W / TS, H / TS, 48);   // 16 x 16 tiles x (B*C = 48) images
    boxsum19_kernel<<<grid, 256, 0, stream>>>(in, out);
}

// Round 2
// 138.545 us; speedup vs baseline: 2.2260x; 2.2260x over previous
//
#include <hip/hip_runtime.h>

// 19x19 box-sum, reflect pad 9, input (16,3,1024,1024) f32.
// V3: V2 structure (horizontal pass global->regs->mid, only `mid` in LDS,
// 21.3 KB -> 7 blocks/CU) with the V2 spill fixed:
//  - launch_bounds(256,6): 85-VGPR budget (V2's (256,7)=73 forced the
//    float v[40] array into scratch: VGPR_Count=36, +117MB scratch writes).
//  - two-batch loads in stage A cap peak live values at ~32.
//  - reflect fallback is per-task (only the actual boundary segment).

#define H    1024
#define W    1024
#define RAD  9
#define TS   64
#define IT   82          // mid rows: TS + 2*RAD
#define MSTR 65          // mid stride: bank=(r+c)%32 diagonal, 2-way max (free)

__global__ __launch_bounds__(256, 6)
void boxsum19_kernel(const float* __restrict__ in, float* __restrict__ out) {
    __shared__ float mid[IT * MSTR];   // 82 x 65 x 4B = 21,320 B

    const int tx0 = blockIdx.x * TS, ty0 = blockIdx.y * TS;
    const size_t img_off = (size_t)blockIdx.z * (size_t)(H * W);
    const float* __restrict__ inp  = in  + img_off;
    float* __restrict__       outp = out + img_off;
    const int tid = threadIdx.x;

    // ---- Stage A: horizontal 19-tap sliding sums, global -> regs -> mid ----
    // 328 tasks: (row r in [0,82)) x (segment s in [0,4)).
    // Task covers mid row r, cols [16s,16s+16); needs global x in
    // [tx0+16s-9, tx0+16s+25); loads the aligned 40-float superset
    // [xb, xb+40), xb = tx0+16s-12 (16B aligned).
    for (int task = tid; task < IT * 4; task += 256) {
        const int r = task >> 2;
        const int s = task & 3;
        int gy = ty0 + r - RAD;
        gy = (gy < 0) ? -gy : ((gy > H - 1) ? (2 * (H - 1) - gy) : gy);
        const float* __restrict__ rowp = inp + (size_t)gy * W;
        const int xb = tx0 + 16 * s - 12;
        float* __restrict__ mrow = &mid[r * MSTR + 16 * s];

        // out(i) = sum v[i+3 .. i+21], i = 0..15
        if (xb >= 0 && xb + 40 <= W) {       // interior segment (fast path)
            float v[40];                      // static indexing only -> VGPRs
            // batch 1: v[0..31]
            #pragma unroll
            for (int q = 0; q < 8; ++q) {
                const float4 f = *reinterpret_cast<const float4*>(rowp + xb + 4 * q);
                v[4*q+0] = f.x; v[4*q+1] = f.y; v[4*q+2] = f.z; v[4*q+3] = f.w;
            }
            float sum = 0.f;
            #pragma unroll
            for (int k = 0; k < 19; ++k) sum += v[3 + k];
            mrow[0] = sum;
            #pragma unroll
            for (int i = 1; i <= 10; ++i) {   // heads v[22..31], tails v[3..12]
                sum += v[21 + i] - v[2 + i];
                mrow[i] = sum;
            }
            // batch 2: v[32..39]
            #pragma unroll
            for (int q = 8; q < 10; ++q) {
                const float4 f = *reinterpret_cast<const float4*>(rowp + xb + 4 * q);
                v[4*q+0] = f.x; v[4*q+1] = f.y; v[4*q+2] = f.z; v[4*q+3] = f.w;
            }
            #pragma unroll
            for (int i = 11; i < 16; ++i) {   // heads v[32..36], tails v[13..17]
                sum += v[21 + i] - v[2 + i];
                mrow[i] = sum;
            }
        } else {                              // boundary segment: reflect-x
            float v[40];
            #pragma unroll
            for (int q = 0; q < 40; ++q) {
                int gx = xb + q;
                gx = (gx < 0) ? -gx : ((gx > W - 1) ? (2 * (W - 1) - gx) : gx);
                v[q] = rowp[gx];
            }
            float sum = 0.f;
            #pragma unroll
            for (int k = 0; k < 19; ++k) sum += v[3 + k];
            mrow[0] = sum;
            #pragma unroll
            for (int i = 1; i < 16; ++i) {
                sum += v[21 + i] - v[2 + i];
                mrow[i] = sum;
            }
        }
    }
    __syncthreads();

    // ---- Stage B: vertical 19-tap sliding sums from mid, coalesced stores ----
    {
        const int c  = tid & 63;
        const int r0 = (tid >> 6) * 16;
        float s = 0.f;
        #pragma unroll
        for (int k = 0; k < 19; ++k) s += mid[(r0 + k) * MSTR + c];
        outp[(size_t)(ty0 + r0) * W + (tx0 + c)] = s;
        #pragma unroll
        for (int i = 1; i < 16; ++i) {
            s += mid[(r0 + 18 + i) * MSTR + c]
               - mid[(r0 + i - 1) * MSTR + c];
            outp[(size_t)(ty0 + r0 + i) * W + (tx0 + c)] = s;
        }
    }
}

extern "C" void kernel_launch(void* const* d_in, const int* in_sizes, int n_in,
                              void* d_out, int out_size, void* d_ws, size_t ws_size,
                              hipStream_t stream) {
    const float* in = (const float*)d_in[0];
    float* out = (float*)d_out;
    dim3 grid(W / TS, H / TS, 48);   // 16 x 16 tiles x (B*C = 48) images
    boxsum19_kernel<<<grid, 256, 0, stream>>>(in, out);
}

// Round 3
// 126.081 us; speedup vs baseline: 2.4461x; 1.0989x over previous
//
#include <hip/hip_runtime.h>

// 19x19 box-sum, reflect pad 9, input (16,3,1024,1024) f32.
// V4: V3 structure (horizontal pass global->float4 regs->mid in LDS,
// vertical pass mid->coalesced stores) scaled to tile 64x128 with
// 512-thread blocks:
//   mid = 146x65x4 = 37,960 B -> 4 blocks/CU x 8 waves = 32 waves/CU (100%)
//   (V3: 256-thread blocks measured only 54% residency -> latency-bound,
//    HBM at 2.76 of 6.3 TB/s. This doubles latency-hiding wave count.)
// __launch_bounds__(512,8) = 64-VGPR budget; V3's two-batch load structure
// compiled to 36 VGPRs, so no spill expected (verify: VGPR_Count, WRITE_SIZE).

#define H    1024
#define W    1024
#define RAD  9
#define TSX  64
#define TSY  128
#define IT   146         // mid rows: TSY + 2*RAD
#define MSTR 65          // mid stride: bank=(r+c)%32 diagonal, 2-way max (free)
#define NT   512

__global__ __launch_bounds__(NT, 8)
void boxsum19_kernel(const float* __restrict__ in, float* __restrict__ out) {
    __shared__ float mid[IT * MSTR];   // 146 x 65 x 4B = 37,960 B

    const int tx0 = blockIdx.x * TSX, ty0 = blockIdx.y * TSY;
    const size_t img_off = (size_t)blockIdx.z * (size_t)(H * W);
    const float* __restrict__ inp  = in  + img_off;
    float* __restrict__       outp = out + img_off;
    const int tid = threadIdx.x;

    // ---- Stage A: horizontal 19-tap sliding sums, global -> regs -> mid ----
    // 584 tasks: (row r in [0,146)) x (segment s in [0,4)).
    // Task covers mid row r, cols [16s,16s+16); loads the aligned 40-float
    // superset [xb, xb+40), xb = tx0+16s-12 (16B aligned).
    for (int task = tid; task < IT * 4; task += NT) {
        const int r = task >> 2;
        const int s = task & 3;
        int gy = ty0 + r - RAD;
        gy = (gy < 0) ? -gy : ((gy > H - 1) ? (2 * (H - 1) - gy) : gy);
        const float* __restrict__ rowp = inp + (size_t)gy * W;
        const int xb = tx0 + 16 * s - 12;
        float* __restrict__ mrow = &mid[r * MSTR + 16 * s];

        // out(i) = sum v[i+3 .. i+21], i = 0..15
        if (xb >= 0 && xb + 40 <= W) {       // interior segment (fast path)
            float v[40];                      // static indexing only -> VGPRs
            // batch 1: v[0..31]  (keeps peak live values ~32 -> fits 64-VGPR)
            #pragma unroll
            for (int q = 0; q < 8; ++q) {
                const float4 f = *reinterpret_cast<const float4*>(rowp + xb + 4 * q);
                v[4*q+0] = f.x; v[4*q+1] = f.y; v[4*q+2] = f.z; v[4*q+3] = f.w;
            }
            float sum = 0.f;
            #pragma unroll
            for (int k = 0; k < 19; ++k) sum += v[3 + k];
            mrow[0] = sum;
            #pragma unroll
            for (int i = 1; i <= 10; ++i) {   // heads v[22..31], tails v[3..12]
                sum += v[21 + i] - v[2 + i];
                mrow[i] = sum;
            }
            // batch 2: v[32..39]
            #pragma unroll
            for (int q = 8; q < 10; ++q) {
                const float4 f = *reinterpret_cast<const float4*>(rowp + xb + 4 * q);
                v[4*q+0] = f.x; v[4*q+1] = f.y; v[4*q+2] = f.z; v[4*q+3] = f.w;
            }
            #pragma unroll
            for (int i = 11; i < 16; ++i) {   // heads v[32..36], tails v[13..17]
                sum += v[21 + i] - v[2 + i];
                mrow[i] = sum;
            }
        } else {                              // boundary segment: reflect-x
            float v[40];
            #pragma unroll
            for (int q = 0; q < 40; ++q) {
                int gx = xb + q;
                gx = (gx < 0) ? -gx : ((gx > W - 1) ? (2 * (W - 1) - gx) : gx);
                v[q] = rowp[gx];
            }
            float sum = 0.f;
            #pragma unroll
            for (int k = 0; k < 19; ++k) sum += v[3 + k];
            mrow[0] = sum;
            #pragma unroll
            for (int i = 1; i < 16; ++i) {
                sum += v[21 + i] - v[2 + i];
                mrow[i] = sum;
            }
        }
    }
    __syncthreads();

    // ---- Stage B: vertical 19-tap sliding sums from mid, coalesced stores ----
    // 512 threads = 64 cols x 8 row-groups of 16 -> perfectly balanced.
    {
        const int c  = tid & 63;
        const int r0 = (tid >> 6) * 16;       // 0,16,...,112
        float s = 0.f;
        #pragma unroll
        for (int k = 0; k < 19; ++k) s += mid[(r0 + k) * MSTR + c];
        outp[(size_t)(ty0 + r0) * W + (tx0 + c)] = s;
        #pragma unroll
        for (int i = 1; i < 16; ++i) {
            s += mid[(r0 + 18 + i) * MSTR + c]
               - mid[(r0 + i - 1) * MSTR + c];
            outp[(size_t)(ty0 + r0 + i) * W + (tx0 + c)] = s;
        }
    }
}

extern "C" void kernel_launch(void* const* d_in, const int* in_sizes, int n_in,
                              void* d_out, int out_size, void* d_ws, size_t ws_size,
                              hipStream_t stream) {
    const float* in = (const float*)d_in[0];
    float* out = (float*)d_out;
    dim3 grid(W / TSX, H / TSY, 48);   // 16 x 8 tiles x (B*C = 48) images
    boxsum19_kernel<<<grid, NT, 0, stream>>>(in, out);
}